// Round 2
// baseline (68.993 us; speedup 1.0000x reference)
//
#include <hip/hip_runtime.h>

#define HH 1024
#define VV 32000
#define SS 2048

__device__ __forceinline__ float wave_sum64(float v) {
    #pragma unroll
    for (int off = 32; off; off >>= 1) v += __shfl_down(v, off, 64);
    return v;
}

__device__ __forceinline__ float sigmoidf(float x) {
    return 1.f / (1.f + expf(-x));
}

// ---------------- Kernel 1: scores[s] = dot(E[s,:], h0); block 0 zeroes ctx ----------------
// 512 blocks x 256 threads = 2048 waves, one row each
__global__ __launch_bounds__(256) void scores_kernel(
    const float* __restrict__ E, const float* __restrict__ h,
    float* __restrict__ scores, float* __restrict__ ctx) {
    int wave = (blockIdx.x * blockDim.x + threadIdx.x) >> 6;
    int lane = threadIdx.x & 63;
    if (blockIdx.x == 0) {
        ((float4*)ctx)[threadIdx.x] = make_float4(0.f, 0.f, 0.f, 0.f);
    }
    const float4* Er = (const float4*)(E + (size_t)wave * HH);
    const float4* hv = (const float4*)h;
    float acc = 0.f;
    #pragma unroll
    for (int k = 0; k < 4; ++k) {
        float4 e = Er[lane + 64 * k];
        float4 x = hv[lane + 64 * k];
        acc += e.x * x.x + e.y * x.y + e.z * x.z + e.w * x.w;
    }
    acc = wave_sum64(acc);
    if (lane == 0) scores[wave] = acc;
}

// ---------------- Kernel 2: full softmax per block + ctx partial (16 rows/block) ----------------
// 128 blocks x 256 threads
__global__ __launch_bounds__(256) void softmax_ctx_kernel(
    const float* __restrict__ E, const float* __restrict__ scores,
    float* __restrict__ attn_out, float* __restrict__ ctx) {
    __shared__ float red[4];
    __shared__ float s_max, s_sum;
    __shared__ float w[16];
    int t = threadIdx.x;
    float4 a = ((const float4*)scores)[t];
    float4 b = ((const float4*)scores)[t + 256];
    // block-wide max over 2048
    float m = fmaxf(fmaxf(fmaxf(a.x, a.y), fmaxf(a.z, a.w)),
                    fmaxf(fmaxf(b.x, b.y), fmaxf(b.z, b.w)));
    #pragma unroll
    for (int off = 32; off; off >>= 1) m = fmaxf(m, __shfl_xor(m, off, 64));
    if ((t & 63) == 0) red[t >> 6] = m;
    __syncthreads();
    if (t == 0) s_max = fmaxf(fmaxf(red[0], red[1]), fmaxf(red[2], red[3]));
    __syncthreads();
    float sm = s_max;
    // block-wide sum of exp
    float sum = expf(a.x - sm) + expf(a.y - sm) + expf(a.z - sm) + expf(a.w - sm)
              + expf(b.x - sm) + expf(b.y - sm) + expf(b.z - sm) + expf(b.w - sm);
    sum = wave_sum64(sum);
    if ((t & 63) == 0) red[t >> 6] = sum;
    __syncthreads();
    if (t == 0) s_sum = red[0] + red[1] + red[2] + red[3];
    __syncthreads();
    float inv = 1.f / s_sum;
    int rowBase = blockIdx.x * 16;
    if (t < 16) {
        float aw = expf(scores[rowBase + t] - sm) * inv;
        w[t] = aw;
        attn_out[rowBase + t] = aw;
    }
    __syncthreads();
    // ctx partial: 16 rows, thread owns float4 column slice
    float4 acc = make_float4(0.f, 0.f, 0.f, 0.f);
    #pragma unroll
    for (int s = 0; s < 16; ++s) {
        float ws_ = w[s];
        float4 e = ((const float4*)(E + (size_t)(rowBase + s) * HH))[t];
        acc.x += ws_ * e.x; acc.y += ws_ * e.y; acc.z += ws_ * e.z; acc.w += ws_ * e.w;
    }
    atomicAdd(&ctx[4 * t + 0], acc.x);
    atomicAdd(&ctx[4 * t + 1], acc.y);
    atomicAdd(&ctx[4 * t + 2], acc.z);
    atomicAdd(&ctx[4 * t + 3], acc.w);
}

// ---------------- Kernel 3: gates0[r] = Wih0[r]·emb_row + Whh0[r]·ctx + b ----------------
// 1024 blocks x 256 threads = 4096 waves, one gate row each
__global__ __launch_bounds__(256) void gates0_kernel(
    const float* __restrict__ Wih, const float* __restrict__ Whh,
    const float* __restrict__ bih, const float* __restrict__ bhh,
    const float* __restrict__ emb, const int* __restrict__ ids,
    const float* __restrict__ ctx, float* __restrict__ gates) {
    int wave = (blockIdx.x * blockDim.x + threadIdx.x) >> 6;
    int lane = threadIdx.x & 63;
    const float* x = emb + (size_t)ids[0] * HH;
    const float4* A  = (const float4*)(Wih + (size_t)wave * HH);
    const float4* B  = (const float4*)(Whh + (size_t)wave * HH);
    const float4* xv = (const float4*)x;
    const float4* hv = (const float4*)ctx;
    float acc = 0.f;
    #pragma unroll
    for (int k = 0; k < 4; ++k) {
        float4 aa = A[lane + 64 * k];
        float4 xx = xv[lane + 64 * k];
        acc += aa.x * xx.x + aa.y * xx.y + aa.z * xx.z + aa.w * xx.w;
        float4 bb = B[lane + 64 * k];
        float4 hh = hv[lane + 64 * k];
        acc += bb.x * hh.x + bb.y * hh.y + bb.z * hh.z + bb.w * hh.w;
    }
    acc = wave_sum64(acc);
    if (lane == 0) gates[wave] = acc + bih[wave] + bhh[wave];
}

// ---------------- Kernel 4: elem0 prologue (h0 -> LDS) + gates1 rows ----------------
// 1024 blocks x 256 threads; each block: h0 prologue, then 4 gate rows (one per wave)
__global__ __launch_bounds__(256) void lstm1_gates_kernel(
    const float* __restrict__ Wih, const float* __restrict__ Whh,
    const float* __restrict__ bih, const float* __restrict__ bhh,
    const float* __restrict__ gates0, const float* __restrict__ c0_in,
    const float* __restrict__ ctx,
    float* __restrict__ h0_out, float* __restrict__ c0_out,
    float* __restrict__ gates1) {
    __shared__ float4 hs[256];
    int t = threadIdx.x;
    {
        float4 gi = ((const float4*)(gates0       ))[t];
        float4 gf = ((const float4*)(gates0 + 1024))[t];
        float4 gg = ((const float4*)(gates0 + 2048))[t];
        float4 go = ((const float4*)(gates0 + 3072))[t];
        float4 cp = ((const float4*)c0_in)[t];
        float4 c4, h4;
        c4.x = sigmoidf(gf.x) * cp.x + sigmoidf(gi.x) * tanhf(gg.x);
        c4.y = sigmoidf(gf.y) * cp.y + sigmoidf(gi.y) * tanhf(gg.y);
        c4.z = sigmoidf(gf.z) * cp.z + sigmoidf(gi.z) * tanhf(gg.z);
        c4.w = sigmoidf(gf.w) * cp.w + sigmoidf(gi.w) * tanhf(gg.w);
        h4.x = sigmoidf(go.x) * tanhf(c4.x);
        h4.y = sigmoidf(go.y) * tanhf(c4.y);
        h4.z = sigmoidf(go.z) * tanhf(c4.z);
        h4.w = sigmoidf(go.w) * tanhf(c4.w);
        hs[t] = h4;
        if (blockIdx.x == 0) {
            ((float4*)h0_out)[t] = h4;
            ((float4*)c0_out)[t] = c4;
        }
    }
    __syncthreads();
    int row  = blockIdx.x * 4 + (t >> 6);
    int lane = t & 63;
    const float4* A  = (const float4*)(Wih + (size_t)row * HH);
    const float4* B  = (const float4*)(Whh + (size_t)row * HH);
    const float4* hv = (const float4*)hs;    // x = h0 (LDS)
    const float4* cv = (const float4*)ctx;   // hprev = ctx
    float acc = 0.f;
    #pragma unroll
    for (int k = 0; k < 4; ++k) {
        float4 aa = A[lane + 64 * k];
        float4 xx = hv[lane + 64 * k];
        acc += aa.x * xx.x + aa.y * xx.y + aa.z * xx.z + aa.w * xx.w;
        float4 bb = B[lane + 64 * k];
        float4 hh = cv[lane + 64 * k];
        acc += bb.x * hh.x + bb.y * hh.y + bb.z * hh.z + bb.w * hh.w;
    }
    acc = wave_sum64(acc);
    if (lane == 0) gates1[row] = acc + bih[row] + bhh[row];
}

// ---------------- Kernel 5: elem1 prologue (h1 -> LDS) + logits rows ----------------
// 8000 blocks x 256 threads; 4 logits rows per block (one per wave)
__global__ __launch_bounds__(256) void logits_fused_kernel(
    const float* __restrict__ W, const float* __restrict__ bout,
    const float* __restrict__ gates1, const float* __restrict__ c1_in,
    float* __restrict__ h1_out, float* __restrict__ c1_out,
    float* __restrict__ out) {
    __shared__ float4 hs[256];
    int t = threadIdx.x;
    {
        float4 gi = ((const float4*)(gates1       ))[t];
        float4 gf = ((const float4*)(gates1 + 1024))[t];
        float4 gg = ((const float4*)(gates1 + 2048))[t];
        float4 go = ((const float4*)(gates1 + 3072))[t];
        float4 cp = ((const float4*)c1_in)[t];
        float4 c4, h4;
        c4.x = sigmoidf(gf.x) * cp.x + sigmoidf(gi.x) * tanhf(gg.x);
        c4.y = sigmoidf(gf.y) * cp.y + sigmoidf(gi.y) * tanhf(gg.y);
        c4.z = sigmoidf(gf.z) * cp.z + sigmoidf(gi.z) * tanhf(gg.z);
        c4.w = sigmoidf(gf.w) * cp.w + sigmoidf(gi.w) * tanhf(gg.w);
        h4.x = sigmoidf(go.x) * tanhf(c4.x);
        h4.y = sigmoidf(go.y) * tanhf(c4.y);
        h4.z = sigmoidf(go.z) * tanhf(c4.z);
        h4.w = sigmoidf(go.w) * tanhf(c4.w);
        hs[t] = h4;
        if (blockIdx.x == 0) {
            ((float4*)h1_out)[t] = h4;
            ((float4*)c1_out)[t] = c4;
        }
    }
    __syncthreads();
    int row  = blockIdx.x * 4 + (t >> 6);
    int lane = t & 63;
    const float4* Wr = (const float4*)(W + (size_t)row * HH);
    const float4* hv = (const float4*)hs;
    float acc = 0.f;
    #pragma unroll
    for (int k = 0; k < 4; ++k) {
        float4 w4 = Wr[lane + 64 * k];
        float4 x4 = hv[lane + 64 * k];
        acc += w4.x * x4.x + w4.y * x4.y + w4.z * x4.z + w4.w * x4.w;
    }
    acc = wave_sum64(acc);
    if (lane == 0) out[row] = acc + bout[row];
}

extern "C" void kernel_launch(void* const* d_in, const int* in_sizes, int n_in,
                              void* d_out, int out_size, void* d_ws, size_t ws_size,
                              hipStream_t stream) {
    const int*   ids   = (const int*)  d_in[0];
    const float* h_in  = (const float*)d_in[1];   // (2,1,H)
    const float* c_in  = (const float*)d_in[2];   // (2,1,H)
    const float* E     = (const float*)d_in[3];   // (S,H)
    const float* emb   = (const float*)d_in[4];   // (V,H)
    const float* Wih0  = (const float*)d_in[5];
    const float* Whh0  = (const float*)d_in[6];
    const float* bih0  = (const float*)d_in[7];
    const float* bhh0  = (const float*)d_in[8];
    const float* Wih1  = (const float*)d_in[9];
    const float* Whh1  = (const float*)d_in[10];
    const float* bih1  = (const float*)d_in[11];
    const float* bhh1  = (const float*)d_in[12];
    const float* Wout  = (const float*)d_in[13];
    const float* bout  = (const float*)d_in[14];

    float* out = (float*)d_out;
    float* logits   = out;                 // 32000
    float* h0_out   = out + 32000;         // 1024
    float* h1_out   = out + 33024;         // 1024
    float* c0_out   = out + 34048;         // 1024
    float* c1_out   = out + 35072;         // 1024
    float* attn_out = out + 36096;         // 2048

    float* ws = (float*)d_ws;
    float* scores  = ws;            // 2048
    float* ctx     = ws + 2048;     // 1024
    float* gates0  = ws + 3072;     // 4096
    float* gates1  = ws + 7168;     // 4096

    // 1: attention scores + zero ctx
    scores_kernel<<<512, 256, 0, stream>>>(E, h_in, scores, ctx);
    // 2: softmax (redundant per block) + ctx = attn @ E
    softmax_ctx_kernel<<<128, 256, 0, stream>>>(E, scores, attn_out, ctx);
    // 3: LSTM0 gates
    gates0_kernel<<<1024, 256, 0, stream>>>(Wih0, Whh0, bih0, bhh0,
                                            emb, ids, ctx, gates0);
    // 4: LSTM0 elementwise (prologue) + LSTM1 gates
    lstm1_gates_kernel<<<1024, 256, 0, stream>>>(Wih1, Whh1, bih1, bhh1,
                                                 gates0, c_in, ctx,
                                                 h0_out, c0_out, gates1);
    // 5: LSTM1 elementwise (prologue) + logits
    logits_fused_kernel<<<8000, 256, 0, stream>>>(Wout, bout, gates1, c_in + 1024,
                                                  h1_out, c1_out, logits);
}

// Round 3
// 60.450 us; speedup vs baseline: 1.1413x; 1.1413x over previous
//
#include <hip/hip_runtime.h>

#define HH 1024
#define VV 32000
#define SS 2048

__device__ __forceinline__ float wave_sum64(float v) {
    #pragma unroll
    for (int off = 32; off; off >>= 1) v += __shfl_down(v, off, 64);
    return v;
}
__device__ __forceinline__ float sigmoidf(float x) { return 1.f / (1.f + expf(-x)); }
__device__ __forceinline__ float dot4(float4 a, float4 b) {
    return a.x * b.x + a.y * b.y + a.z * b.z + a.w * b.w;
}

// ---------------- K1: scores[s]=E[s]·h ; g0[r]=Wih0[r]·x + biases ; zero ctx ----------------
// 512 blocks x 256 = 2048 waves. Wave w: scores row w, g0 rows w and w+2048.
__global__ __launch_bounds__(256) void k1_scores_g0(
    const float* __restrict__ E, const float* __restrict__ h,
    const float* __restrict__ Wih0, const float* __restrict__ bih0,
    const float* __restrict__ bhh0,
    const float* __restrict__ emb, const int* __restrict__ ids,
    float* __restrict__ scores, float* __restrict__ g0, float* __restrict__ ctx) {
    int tid = threadIdx.x;
    int w = (blockIdx.x * 256 + tid) >> 6;
    int lane = tid & 63;
    if (blockIdx.x == 0) ((float4*)ctx)[tid] = make_float4(0.f, 0.f, 0.f, 0.f);

    const float4* hv = (const float4*)h;
    float4 h0 = hv[lane], h1 = hv[lane + 64], h2 = hv[lane + 128], h3 = hv[lane + 192];
    const float4* Er = (const float4*)(E + (size_t)w * HH);
    float acc = dot4(Er[lane], h0) + dot4(Er[lane + 64], h1)
              + dot4(Er[lane + 128], h2) + dot4(Er[lane + 192], h3);
    acc = wave_sum64(acc);
    if (lane == 0) scores[w] = acc;

    const float4* xv = (const float4*)(emb + (size_t)ids[0] * HH);
    float4 x0 = xv[lane], x1 = xv[lane + 64], x2 = xv[lane + 128], x3 = xv[lane + 192];
    #pragma unroll
    for (int t = 0; t < 2; ++t) {
        int row = w + t * 2048;
        const float4* Wr = (const float4*)(Wih0 + (size_t)row * HH);
        float a = dot4(Wr[lane], x0) + dot4(Wr[lane + 64], x1)
                + dot4(Wr[lane + 128], x2) + dot4(Wr[lane + 192], x3);
        a = wave_sum64(a);
        if (lane == 0) g0[row] = a + bih0[row] + bhh0[row];
    }
}

// ---------------- K2: full softmax per block + ctx partial (16 rows/block) ----------------
// 128 blocks x 256 threads (unchanged from R2 — proven correct)
__global__ __launch_bounds__(256) void softmax_ctx_kernel(
    const float* __restrict__ E, const float* __restrict__ scores,
    float* __restrict__ attn_out, float* __restrict__ ctx) {
    __shared__ float red[4];
    __shared__ float s_max, s_sum;
    __shared__ float w[16];
    int t = threadIdx.x;
    float4 a = ((const float4*)scores)[t];
    float4 b = ((const float4*)scores)[t + 256];
    float m = fmaxf(fmaxf(fmaxf(a.x, a.y), fmaxf(a.z, a.w)),
                    fmaxf(fmaxf(b.x, b.y), fmaxf(b.z, b.w)));
    #pragma unroll
    for (int off = 32; off; off >>= 1) m = fmaxf(m, __shfl_xor(m, off, 64));
    if ((t & 63) == 0) red[t >> 6] = m;
    __syncthreads();
    if (t == 0) s_max = fmaxf(fmaxf(red[0], red[1]), fmaxf(red[2], red[3]));
    __syncthreads();
    float sm = s_max;
    float sum = expf(a.x - sm) + expf(a.y - sm) + expf(a.z - sm) + expf(a.w - sm)
              + expf(b.x - sm) + expf(b.y - sm) + expf(b.z - sm) + expf(b.w - sm);
    sum = wave_sum64(sum);
    if ((t & 63) == 0) red[t >> 6] = sum;
    __syncthreads();
    if (t == 0) s_sum = red[0] + red[1] + red[2] + red[3];
    __syncthreads();
    float inv = 1.f / s_sum;
    int rowBase = blockIdx.x * 16;
    if (t < 16) {
        float aw = expf(scores[rowBase + t] - sm) * inv;
        w[t] = aw;
        attn_out[rowBase + t] = aw;
    }
    __syncthreads();
    float4 acc = make_float4(0.f, 0.f, 0.f, 0.f);
    #pragma unroll
    for (int s = 0; s < 16; ++s) {
        float ws_ = w[s];
        float4 e = ((const float4*)(E + (size_t)(rowBase + s) * HH))[t];
        acc.x += ws_ * e.x; acc.y += ws_ * e.y; acc.z += ws_ * e.z; acc.w += ws_ * e.w;
    }
    atomicAdd(&ctx[4 * t + 0], acc.x);
    atomicAdd(&ctx[4 * t + 1], acc.y);
    atomicAdd(&ctx[4 * t + 2], acc.z);
    atomicAdd(&ctx[4 * t + 3], acc.w);
}

// ---------------- K3: g0[w] += Whh0[w]·ctx ; g1[w] = Whh1[w]·ctx + biases1 ----------------
// 1024 blocks x 256 = 4096 waves, one row index each (both matrices)
__global__ __launch_bounds__(256) void k3_whh(
    const float* __restrict__ Whh0, const float* __restrict__ Whh1,
    const float* __restrict__ bih1, const float* __restrict__ bhh1,
    const float* __restrict__ ctx, float* __restrict__ g0, float* __restrict__ g1) {
    int tid = threadIdx.x;
    int w = (blockIdx.x * 256 + tid) >> 6;
    int lane = tid & 63;
    const float4* cv = (const float4*)ctx;
    float4 c0 = cv[lane], c1 = cv[lane + 64], c2 = cv[lane + 128], c3 = cv[lane + 192];
    const float4* W0 = (const float4*)(Whh0 + (size_t)w * HH);
    float a = dot4(W0[lane], c0) + dot4(W0[lane + 64], c1)
            + dot4(W0[lane + 128], c2) + dot4(W0[lane + 192], c3);
    a = wave_sum64(a);
    const float4* W1 = (const float4*)(Whh1 + (size_t)w * HH);
    float b = dot4(W1[lane], c0) + dot4(W1[lane + 64], c1)
            + dot4(W1[lane + 128], c2) + dot4(W1[lane + 192], c3);
    b = wave_sum64(b);
    if (lane == 0) {
        g0[w] += a;
        g1[w] = b + bih1[w] + bhh1[w];
    }
}

// ---------------- K4: elem0 prologue (block-redundant) + g1[row] += Wih1[row]·h0 ----------------
// 512 blocks x 256; block owns 8 rows (2 per wave). W row-0 chunk preloaded before prologue.
__global__ __launch_bounds__(256) void k4_gates1(
    const float* __restrict__ Wih1, const float* __restrict__ g0,
    const float* __restrict__ c0_in, float* __restrict__ g1,
    float* __restrict__ h0_out, float* __restrict__ c0_out) {
    __shared__ float4 hs[256];
    int tid = threadIdx.x, warp = tid >> 6, lane = tid & 63;
    int row0 = blockIdx.x * 8 + warp * 2;
    const float4* Wr = (const float4*)(Wih1 + (size_t)row0 * HH);
    float4 a0 = Wr[lane], a1 = Wr[lane + 64], a2 = Wr[lane + 128], a3 = Wr[lane + 192];
    {
        float4 gi = ((const float4*)(g0       ))[tid];
        float4 gf = ((const float4*)(g0 + 1024))[tid];
        float4 gg = ((const float4*)(g0 + 2048))[tid];
        float4 go = ((const float4*)(g0 + 3072))[tid];
        float4 cp = ((const float4*)c0_in)[tid];
        float4 c4, h4;
        c4.x = sigmoidf(gf.x) * cp.x + sigmoidf(gi.x) * tanhf(gg.x);
        c4.y = sigmoidf(gf.y) * cp.y + sigmoidf(gi.y) * tanhf(gg.y);
        c4.z = sigmoidf(gf.z) * cp.z + sigmoidf(gi.z) * tanhf(gg.z);
        c4.w = sigmoidf(gf.w) * cp.w + sigmoidf(gi.w) * tanhf(gg.w);
        h4.x = sigmoidf(go.x) * tanhf(c4.x);
        h4.y = sigmoidf(go.y) * tanhf(c4.y);
        h4.z = sigmoidf(go.z) * tanhf(c4.z);
        h4.w = sigmoidf(go.w) * tanhf(c4.w);
        hs[tid] = h4;
        if (blockIdx.x == 0) {
            ((float4*)h0_out)[tid] = h4;
            ((float4*)c0_out)[tid] = c4;
        }
    }
    __syncthreads();
    float4 x0 = hs[lane], x1 = hs[lane + 64], x2 = hs[lane + 128], x3 = hs[lane + 192];
    float acc0 = dot4(a0, x0) + dot4(a1, x1) + dot4(a2, x2) + dot4(a3, x3);
    acc0 = wave_sum64(acc0);
    if (lane == 0) g1[row0] += acc0;
    const float4* W2 = Wr + 256;
    float acc1 = dot4(W2[lane], x0) + dot4(W2[lane + 64], x1)
               + dot4(W2[lane + 128], x2) + dot4(W2[lane + 192], x3);
    acc1 = wave_sum64(acc1);
    if (lane == 0) g1[row0 + 1] += acc1;
}

// ---------------- K5: elem1 prologue (block-redundant) + logits, 8 rows/wave pipelined ----------------
// 1000 blocks x 256; block owns 32 rows; wave streams 32KB of W with 1-deep preload.
__global__ __launch_bounds__(256) void k5_logits(
    const float* __restrict__ W, const float* __restrict__ bout,
    const float* __restrict__ g1, const float* __restrict__ c1_in,
    float* __restrict__ h1_out, float* __restrict__ c1_out,
    float* __restrict__ out) {
    __shared__ float4 hs[256];
    int tid = threadIdx.x, warp = tid >> 6, lane = tid & 63;
    int row0 = blockIdx.x * 32 + warp * 8;
    const float4* Wr = (const float4*)(W + (size_t)row0 * HH);
    float4 a0 = Wr[lane], a1 = Wr[lane + 64], a2 = Wr[lane + 128], a3 = Wr[lane + 192];
    {
        float4 gi = ((const float4*)(g1       ))[tid];
        float4 gf = ((const float4*)(g1 + 1024))[tid];
        float4 gg = ((const float4*)(g1 + 2048))[tid];
        float4 go = ((const float4*)(g1 + 3072))[tid];
        float4 cp = ((const float4*)c1_in)[tid];
        float4 c4, h4;
        c4.x = sigmoidf(gf.x) * cp.x + sigmoidf(gi.x) * tanhf(gg.x);
        c4.y = sigmoidf(gf.y) * cp.y + sigmoidf(gi.y) * tanhf(gg.y);
        c4.z = sigmoidf(gf.z) * cp.z + sigmoidf(gi.z) * tanhf(gg.z);
        c4.w = sigmoidf(gf.w) * cp.w + sigmoidf(gi.w) * tanhf(gg.w);
        h4.x = sigmoidf(go.x) * tanhf(c4.x);
        h4.y = sigmoidf(go.y) * tanhf(c4.y);
        h4.z = sigmoidf(go.z) * tanhf(c4.z);
        h4.w = sigmoidf(go.w) * tanhf(c4.w);
        hs[tid] = h4;
        if (blockIdx.x == 0) {
            ((float4*)h1_out)[tid] = h4;
            ((float4*)c1_out)[tid] = c4;
        }
    }
    __syncthreads();
    float4 x0 = hs[lane], x1 = hs[lane + 64], x2 = hs[lane + 128], x3 = hs[lane + 192];
    #pragma unroll
    for (int i = 0; i < 8; ++i) {
        float4 b0 = a0, b1 = a1, b2 = a2, b3 = a3;
        if (i < 7) {
            const float4* Nx = Wr + (i + 1) * 256;
            b0 = Nx[lane]; b1 = Nx[lane + 64]; b2 = Nx[lane + 128]; b3 = Nx[lane + 192];
        }
        float acc = dot4(a0, x0) + dot4(a1, x1) + dot4(a2, x2) + dot4(a3, x3);
        acc = wave_sum64(acc);
        if (lane == 0) out[row0 + i] = acc + bout[row0 + i];
        a0 = b0; a1 = b1; a2 = b2; a3 = b3;
    }
}

extern "C" void kernel_launch(void* const* d_in, const int* in_sizes, int n_in,
                              void* d_out, int out_size, void* d_ws, size_t ws_size,
                              hipStream_t stream) {
    const int*   ids   = (const int*)  d_in[0];
    const float* h_in  = (const float*)d_in[1];   // (2,1,H)
    const float* c_in  = (const float*)d_in[2];   // (2,1,H)
    const float* E     = (const float*)d_in[3];   // (S,H)
    const float* emb   = (const float*)d_in[4];   // (V,H)
    const float* Wih0  = (const float*)d_in[5];
    const float* Whh0  = (const float*)d_in[6];
    const float* bih0  = (const float*)d_in[7];
    const float* bhh0  = (const float*)d_in[8];
    const float* Wih1  = (const float*)d_in[9];
    const float* Whh1  = (const float*)d_in[10];
    const float* bih1  = (const float*)d_in[11];
    const float* bhh1  = (const float*)d_in[12];
    const float* Wout  = (const float*)d_in[13];
    const float* bout  = (const float*)d_in[14];

    float* out = (float*)d_out;
    float* logits   = out;                 // 32000
    float* h0_out   = out + 32000;         // 1024
    float* h1_out   = out + 33024;         // 1024
    float* c0_out   = out + 34048;         // 1024
    float* c1_out   = out + 35072;         // 1024
    float* attn_out = out + 36096;         // 2048

    float* ws = (float*)d_ws;
    float* scores = ws;            // 2048
    float* ctx    = ws + 2048;     // 1024
    float* g0     = ws + 3072;     // 4096 (Wih0·x + biases, then += Whh0·ctx)
    float* g1     = ws + 7168;     // 4096 (Whh1·ctx + biases1, then += Wih1·h0)

    // K1: scores + independent half of gates0 + zero ctx
    k1_scores_g0<<<512, 256, 0, stream>>>(E, h_in, Wih0, bih0, bhh0,
                                          emb, ids, scores, g0, ctx);
    // K2: softmax + ctx = attn @ E
    softmax_ctx_kernel<<<128, 256, 0, stream>>>(E, scores, attn_out, ctx);
    // K3: both ctx-dependent matvec halves (finishes gates0, preps gates1)
    k3_whh<<<1024, 256, 0, stream>>>(Whh0, Whh1, bih1, bhh1, ctx, g0, g1);
    // K4: elem0 + Wih1·h0 (finishes gates1)
    k4_gates1<<<512, 256, 0, stream>>>(Wih1, g0, c_in, g1, h0_out, c0_out);
    // K5: elem1 + logits
    k5_logits<<<1000, 256, 0, stream>>>(Wout, bout, g1, c_in + 1024,
                                        h1_out, c1_out, logits);
}